// Round 3
// baseline (146.653 us; speedup 1.0000x reference)
//
#include <hip/hip_runtime.h>
#include <math.h>

#define L2C 25
#define CH  128
#define NB  8
#define GLB 7
#define GLA 13
#define NG  91
#define GPAD 96
#define KPAD 32

typedef short bf16x8 __attribute__((ext_vector_type(8)));
typedef int   i32x4  __attribute__((ext_vector_type(4)));
typedef float f32x4  __attribute__((ext_vector_type(4)));

union frag_u { i32x4 i; bf16x8 h; };

__device__ inline short f2bf(float f) {
  union { float f; unsigned u; } v; v.f = f;
  unsigned r = (v.u + 0x7FFFu + ((v.u >> 16) & 1u)) >> 16;
  return (short)r;
}
__device__ inline unsigned cvt_pk_bf16(float lo, float hi) {
  unsigned r; asm volatile("v_cvt_pk_bf16_f32 %0, %1, %2" : "=v"(r) : "v"(lo), "v"(hi)); return r;
}

// ---------------- SH tables (bf16), built on device ----------------
__global__ void build_tables_kernel(short* __restrict__ toT, short* __restrict__ frT) {
  const int g = threadIdx.x;
  if (g >= GPAD) return;
  const double PI = 3.14159265358979323846;
  double Y[L2C];
  double wg = 0.0;
  if (g < NG) {
    const int b = g / GLA;
    const int a = g % GLA;
    double xx = cos(PI * (b + 0.75) / (GLB + 0.5));
    double pp = 1.0;
    for (int it = 0; it < 64; ++it) {
      double p0 = 1.0, p1 = xx;
      for (int j = 2; j <= GLB; ++j) { double p2 = ((2.0*j-1.0)*xx*p1 - (j-1.0)*p0)/j; p0 = p1; p1 = p2; }
      pp = GLB * (xx*p1 - p0) / (xx*xx - 1.0);
      xx -= p1 / pp;
    }
    { double p0 = 1.0, p1 = xx;
      for (int j = 2; j <= GLB; ++j) { double p2 = ((2.0*j-1.0)*xx*p1 - (j-1.0)*p0)/j; p0 = p1; p1 = p2; }
      pp = GLB * (xx*p1 - p0) / (xx*xx - 1.0); }
    const double wb = 2.0 / ((1.0 - xx*xx) * pp * pp);
    const double ct = xx;
    const double sx = sqrt(fmax(0.0, 1.0 - ct*ct));
    double P[5][5];
    P[0][0] = 1.0;
    for (int m = 1; m <= 4; ++m) P[m][m] = -(2.0*m - 1.0) * sx * P[m-1][m-1];
    for (int m = 0; m <= 3; ++m) P[m+1][m] = (2.0*m + 1.0) * ct * P[m][m];
    for (int m = 0; m <= 4; ++m)
      for (int l = m + 2; l <= 4; ++l)
        P[l][m] = ((2.0*l-1.0)*ct*P[l-1][m] - (l+m-1.0)*P[l-2][m]) / (l - m);
    const double fact[9] = {1,1,2,6,24,120,720,5040,40320};
    const double phi = (2.0*PI/GLA) * a;
    for (int l = 0; l <= 4; ++l)
      for (int m = 0; m <= l; ++m) {
        double Nlm = sqrt((2.0*l+1.0)/(4.0*PI) * fact[l-m]/fact[l+m]);
        if (m == 0) Y[l*l + l] = Nlm * P[l][0];
        else {
          double base = sqrt(2.0) * Nlm * P[l][m];
          Y[l*l + l + m] = base * cos((double)m * phi);
          Y[l*l + l - m] = base * sin((double)m * phi);
        }
      }
    wg = wb * (2.0*PI/GLA);
  }
  for (int l = 0; l < KPAD; ++l) {
    float tv = (g < NG && l < L2C) ? (float)Y[l] : 0.f;
    toT[g*KPAD + l] = f2bf(tv);
  }
  for (int l = 0; l < KPAD; ++l) {
    float fv = (g < NG && l < L2C) ? (float)(wg * Y[l]) : 0.f;
    frT[l*GPAD + g] = f2bf(fv);
  }
}

__global__ void convert_w_kernel(const float* __restrict__ w1, const float* __restrict__ w2,
                                 short* __restrict__ wb1, short* __restrict__ wb2) {
  const int i = blockIdx.x * 256 + threadIdx.x;
  if (i < 5*CH*CH) { wb1[i] = f2bf(w1[i]); wb2[i] = f2bf(w2[i]); }
}

// ================= K1: LayerNorm + linear1 -> hg (global bf16) =================
__global__ __launch_bounds__(512, 4) void k1_ln_lin1(
    const float* __restrict__ x,
    const float* __restrict__ norm_w, const float* __restrict__ norm_b,
    const short* __restrict__ wb1, const float* __restrict__ b1,
    short* __restrict__ hg)
{
  __shared__ __align__(16) short hsh[16][242][8];   // ~62 KB

  const int tid  = threadIdx.x;
  const int w    = tid >> 6;
  const int lane = tid & 63;
  const int l16  = lane & 15;
  const int lq   = lane >> 4;
  const long n0  = (long)blockIdx.x * NB;

  constexpr int LDEG[L2C] = {0,1,1,1,2,2,2,2,2,3,3,3,3,3,3,3,4,4,4,4,4,4,4,4,4};
  constexpr int BROW[5]   = {0,16,48,96,160};

  // ---- LayerNorm: wave w owns node w ----
  {
    const float* xn = x + (n0 + w) * (L2C*CH);
    const float2* x2 = (const float2*)xn;
    float s0 = 0.f, s0q = 0.f, sq = 0.f;
    for (int j = lane; j < L2C*CH/2; j += 64) {
      const float2 v = x2[j];
      const float t = v.x*v.x + v.y*v.y;
      if (j < 64) { s0 += v.x + v.y; s0q += t; }
      else        sq += t;
    }
    #pragma unroll
    for (int o = 1; o < 64; o <<= 1) {
      s0  += __shfl_xor(s0,  o, 64);
      s0q += __shfl_xor(s0q, o, 64);
      sq  += __shfl_xor(sq,  o, 64);
    }
    const float mean0 = s0 * (1.f/CH);
    const float var   = (sq + s0q - CH*mean0*mean0) * (1.f/(L2C*CH));
    const float rstd  = rsqrtf(var + 1e-5f);
    #pragma unroll
    for (int s = 0; s < L2C; ++s) {
      const int d   = LDEG[s];
      const int row = BROW[d] + (s - d*d)*NB + w;
      const float2 v = x2[s*64 + lane];
      const int c0 = 2*lane;
      float a0 = v.x, a1 = v.y;
      if (s == 0) { a0 -= mean0; a1 -= mean0; }
      a0 *= rstd * norm_w[d*CH + c0];
      a1 *= rstd * norm_w[d*CH + c0 + 1];
      if (s == 0) { a0 += norm_b[c0]; a1 += norm_b[c0+1]; }
      const unsigned pk = (unsigned)(unsigned short)f2bf(a0) | ((unsigned)(unsigned short)f2bf(a1) << 16);
      *(unsigned*)&hsh[c0 >> 3][row][c0 & 7] = pk;
    }
  }
  __syncthreads();

  // ---- linear1 -> hg global [grp][node][s>>3][c=k][s&7] ----
  {
    const int k = w*16 + l16;
    short* hgB = hg + (long)blockIdx.x * (NB*4*CH*8);
    #pragma unroll
    for (int d = 0; d < 5; ++d) {
      frag_u B[4];
      #pragma unroll
      for (int ks = 0; ks < 4; ++ks)
        B[ks].i = *(const i32x4*)(wb1 + ((d*CH + k)*CH + ks*32 + lq*8));
      #pragma unroll
      for (int mt = 0; mt <= d; ++mt) {
        const int rowbase = BROW[d] + mt*16;
        f32x4 acc = {0.f, 0.f, 0.f, 0.f};
        #pragma unroll
        for (int ks = 0; ks < 4; ++ks) {
          const bf16x8 a = *(const bf16x8*)&hsh[ks*4 + lq][rowbase + l16][0];
          acc = __builtin_amdgcn_mfma_f32_16x16x32_bf16(a, B[ks].h, acc, 0, 0, 0);
        }
        #pragma unroll
        for (int i = 0; i < 4; ++i) {
          const int rr   = mt*16 + lq*4 + i;
          const int node = rr & 7, sl = rr >> 3;
          if (sl <= 2*d) {
            const int s = d*d + sl;
            const float vv = acc[i] + ((s == 0) ? b1[k] : 0.f);
            hgB[(node*4 + (s >> 3))*(CH*8) + k*8 + (s & 7)] = f2bf(vv);
          }
        }
      }
    }
  }
}

// ================= K2: Gaunt (registers + bpermute) + linear2 + residual =================
__global__ __launch_bounds__(512, 4) void k2_gaunt_lin2(
    const float* __restrict__ x,
    const short* __restrict__ hg,
    const float* __restrict__ w_tp,
    const short* __restrict__ wb2, const float* __restrict__ b2,
    const short* __restrict__ toT, const short* __restrict__ frT,
    float* __restrict__ out)
{
  __shared__ __align__(16) short hsh[16][242][8];   // ~62 KB (Gaunt out -> linear2 A staging)

  const int tid  = threadIdx.x;
  const int w    = tid >> 6;
  const int lane = tid & 63;
  const int l16  = lane & 15;
  const int lq   = lane >> 4;
  const long n0  = (long)blockIdx.x * NB;

  constexpr int LDEG[L2C] = {0,1,1,1,2,2,2,2,2,3,3,3,3,3,3,3,4,4,4,4,4,4,4,4,4};
  constexpr int BROW[5]   = {0,16,48,96,160};

  const int cw = w*16 + l16;
  const bool hi32 = (lane >= 32);
  // bpermute byte-indices: lane_src = l16 + 16*((lq&1)*2 + (jj>>1))
  const int idxA = (l16 + 32*(lq & 1)) * 4;   // jj = 0,1
  const int idxB = idxA + 64;                 // jj = 2,3

  // per-lane epilogue constants
  float wtp[2][4]; int hrow[2][4];
  #pragma unroll
  for (int mt = 0; mt < 2; ++mt)
    #pragma unroll
    for (int i = 0; i < 4; ++i) {
      const int l = mt*16 + lq*4 + i;
      if (l < L2C) {
        const int d = LDEG[l];
        wtp[mt][i]  = w_tp[d*CH + cw];
        hrow[mt][i] = BROW[d] + (l - d*d)*NB;
      } else { wtp[mt][i] = 0.f; hrow[mt][i] = -1; }
    }

  // ---- Gaunt per node, fully in registers ----
  const short* hgB = hg + (long)blockIdx.x * (NB*4*CH*8);
  for (int node = 0; node < NB; ++node) {
    frag_u Bh;
    Bh.i = *(const i32x4*)(hgB + (node*4 + lq)*(CH*8) + cw*8);

    unsigned p[6][2];
    #pragma unroll
    for (int gt = 0; gt < 6; ++gt) {
      frag_u Ato;
      Ato.i = *(const i32x4*)(toT + (gt*16 + l16)*KPAD + lq*8);
      f32x4 acc = {0.f, 0.f, 0.f, 0.f};
      acc = __builtin_amdgcn_mfma_f32_16x16x32_bf16(Ato.h, Bh.h, acc, 0, 0, 0);
      p[gt][0] = cvt_pk_bf16(acc[0]*acc[0], acc[1]*acc[1]);
      p[gt][1] = cvt_pk_bf16(acc[2]*acc[2], acc[3]*acc[3]);
    }

    f32x4 acc2[2] = {{0.f,0.f,0.f,0.f},{0.f,0.f,0.f,0.f}};
    #pragma unroll
    for (int ks = 0; ks < 3; ++ks) {
      // build B-frag of squared grid values for g = ks*32 + lq*8 + [0..8)
      frag_u Bg;
      {
        const int lo0 = __builtin_amdgcn_ds_bpermute(idxA, (int)p[2*ks][0]);
        const int hi0 = __builtin_amdgcn_ds_bpermute(idxA, (int)p[2*ks+1][0]);
        const int lo1 = __builtin_amdgcn_ds_bpermute(idxA, (int)p[2*ks][1]);
        const int hi1 = __builtin_amdgcn_ds_bpermute(idxA, (int)p[2*ks+1][1]);
        const int lo2 = __builtin_amdgcn_ds_bpermute(idxB, (int)p[2*ks][0]);
        const int hi2 = __builtin_amdgcn_ds_bpermute(idxB, (int)p[2*ks+1][0]);
        const int lo3 = __builtin_amdgcn_ds_bpermute(idxB, (int)p[2*ks][1]);
        const int hi3 = __builtin_amdgcn_ds_bpermute(idxB, (int)p[2*ks+1][1]);
        Bg.i[0] = hi32 ? hi0 : lo0;
        Bg.i[1] = hi32 ? hi1 : lo1;
        Bg.i[2] = hi32 ? hi2 : lo2;
        Bg.i[3] = hi32 ? hi3 : lo3;
      }
      #pragma unroll
      for (int mt = 0; mt < 2; ++mt) {
        frag_u Afr;
        Afr.i = *(const i32x4*)(frT + (mt*16 + l16)*GPAD + ks*32 + lq*8);
        acc2[mt] = __builtin_amdgcn_mfma_f32_16x16x32_bf16(Afr.h, Bg.h, acc2[mt], 0, 0, 0);
      }
    }
    #pragma unroll
    for (int mt = 0; mt < 2; ++mt)
      #pragma unroll
      for (int i = 0; i < 4; ++i)
        if (hrow[mt][i] >= 0)
          hsh[cw >> 3][hrow[mt][i] + node][cw & 7] = f2bf(acc2[mt][i] * wtp[mt][i]);
  }
  __syncthreads();

  // ---- linear2 + bias(l=0) + residual -> out ----
  {
    const int k = cw;
    #pragma unroll
    for (int d = 0; d < 5; ++d) {
      frag_u B[4];
      #pragma unroll
      for (int ks = 0; ks < 4; ++ks)
        B[ks].i = *(const i32x4*)(wb2 + ((d*CH + k)*CH + ks*32 + lq*8));
      #pragma unroll
      for (int mt = 0; mt <= d; ++mt) {
        const int rowbase = BROW[d] + mt*16;
        f32x4 acc = {0.f, 0.f, 0.f, 0.f};
        #pragma unroll
        for (int ks = 0; ks < 4; ++ks) {
          const bf16x8 a = *(const bf16x8*)&hsh[ks*4 + lq][rowbase + l16][0];
          acc = __builtin_amdgcn_mfma_f32_16x16x32_bf16(a, B[ks].h, acc, 0, 0, 0);
        }
        #pragma unroll
        for (int i = 0; i < 4; ++i) {
          const int rr   = mt*16 + lq*4 + i;
          const int node = rr & 7, sl = rr >> 3;
          if (sl <= 2*d) {
            const int s = d*d + sl;
            const long base = (n0 + node)*(long)(L2C*CH) + s*CH + k;
            out[base] = acc[i] + ((s == 0) ? b2[k] : 0.f) + x[base];
          }
        }
      }
    }
  }
}

// ---------------- launch ----------------
extern "C" void kernel_launch(void* const* d_in, const int* in_sizes, int n_in,
                              void* d_out, int out_size, void* d_ws, size_t ws_size,
                              hipStream_t stream) {
  const float* x      = (const float*)d_in[0];
  // d_in[1] = batch (unused)
  const float* norm_w = (const float*)d_in[2];
  const float* norm_b = (const float*)d_in[3];
  const float* w1     = (const float*)d_in[4];
  const float* b1     = (const float*)d_in[5];
  const float* w_tp   = (const float*)d_in[6];
  const float* w2     = (const float*)d_in[7];
  const float* b2     = (const float*)d_in[8];
  float* out = (float*)d_out;

  const int N = in_sizes[0] / (L2C*CH);   // 6000
  const int NGRP = N / NB;                // 750

  short* wsS = (short*)d_ws;              // needs ~49.5 MB
  short* toT = wsS;                       // [96][32]
  short* frT = toT + GPAD*KPAD;           // [32][96]
  short* wb1 = frT + KPAD*GPAD;           // [5][128][128]
  short* wb2 = wb1 + 5*CH*CH;
  short* hg  = wb2 + 5*CH*CH;             // [750][8][4][128][8] bf16 = 49.15 MB

  build_tables_kernel<<<1, 128, 0, stream>>>(toT, frT);
  convert_w_kernel<<<(5*CH*CH + 255)/256, 256, 0, stream>>>(w1, w2, wb1, wb2);
  k1_ln_lin1<<<NGRP, 512, 0, stream>>>(x, norm_w, norm_b, wb1, b1, hg);
  k2_gaunt_lin2<<<NGRP, 512, 0, stream>>>(x, hg, w_tp, wb2, b2, toT, frT, out);
}

// Round 4
// 142.626 us; speedup vs baseline: 1.0282x; 1.0282x over previous
//
#include <hip/hip_runtime.h>
#include <math.h>

#define L2C 25
#define CH  128
#define NB  4
#define GLB 7
#define GLA 13
#define NG  91
#define GPAD 96
#define KPAD 32
#define HROWS 147      // 144 used rows + 3 pad (odd count staggers LDS banks)

typedef short bf16x8 __attribute__((ext_vector_type(8)));
typedef short short4v __attribute__((ext_vector_type(4)));
typedef int   i32x4  __attribute__((ext_vector_type(4)));
typedef float f32x4  __attribute__((ext_vector_type(4)));

union frag_u { i32x4 i; bf16x8 h; };

__device__ inline short f2bf(float f) {
  union { float f; unsigned u; } v; v.f = f;
  unsigned r = (v.u + 0x7FFFu + ((v.u >> 16) & 1u)) >> 16;
  return (short)r;
}
__device__ inline unsigned cvt_pk_bf16(float lo, float hi) {
  unsigned r; asm volatile("v_cvt_pk_bf16_f32 %0, %1, %2" : "=v"(r) : "v"(lo), "v"(hi)); return r;
}

// ---------------- SH tables (bf16), built on device ----------------
__global__ void build_tables_kernel(short* __restrict__ toT, short* __restrict__ frT) {
  const int g = threadIdx.x;
  if (g >= GPAD) return;
  const double PI = 3.14159265358979323846;
  double Y[L2C];
  double wg = 0.0;
  if (g < NG) {
    const int b = g / GLA;
    const int a = g % GLA;
    double xx = cos(PI * (b + 0.75) / (GLB + 0.5));
    double pp = 1.0;
    for (int it = 0; it < 64; ++it) {
      double p0 = 1.0, p1 = xx;
      for (int j = 2; j <= GLB; ++j) { double p2 = ((2.0*j-1.0)*xx*p1 - (j-1.0)*p0)/j; p0 = p1; p1 = p2; }
      pp = GLB * (xx*p1 - p0) / (xx*xx - 1.0);
      xx -= p1 / pp;
    }
    { double p0 = 1.0, p1 = xx;
      for (int j = 2; j <= GLB; ++j) { double p2 = ((2.0*j-1.0)*xx*p1 - (j-1.0)*p0)/j; p0 = p1; p1 = p2; }
      pp = GLB * (xx*p1 - p0) / (xx*xx - 1.0); }
    const double wb = 2.0 / ((1.0 - xx*xx) * pp * pp);
    const double ct = xx;
    const double sx = sqrt(fmax(0.0, 1.0 - ct*ct));
    double P[5][5];
    P[0][0] = 1.0;
    for (int m = 1; m <= 4; ++m) P[m][m] = -(2.0*m - 1.0) * sx * P[m-1][m-1];
    for (int m = 0; m <= 3; ++m) P[m+1][m] = (2.0*m + 1.0) * ct * P[m][m];
    for (int m = 0; m <= 4; ++m)
      for (int l = m + 2; l <= 4; ++l)
        P[l][m] = ((2.0*l-1.0)*ct*P[l-1][m] - (l+m-1.0)*P[l-2][m]) / (l - m);
    const double fact[9] = {1,1,2,6,24,120,720,5040,40320};
    const double phi = (2.0*PI/GLA) * a;
    for (int l = 0; l <= 4; ++l)
      for (int m = 0; m <= l; ++m) {
        double Nlm = sqrt((2.0*l+1.0)/(4.0*PI) * fact[l-m]/fact[l+m]);
        if (m == 0) Y[l*l + l] = Nlm * P[l][0];
        else {
          double base = sqrt(2.0) * Nlm * P[l][m];
          Y[l*l + l + m] = base * cos((double)m * phi);
          Y[l*l + l - m] = base * sin((double)m * phi);
        }
      }
    wg = wb * (2.0*PI/GLA);
  }
  for (int l = 0; l < KPAD; ++l) {
    float tv = (g < NG && l < L2C) ? (float)Y[l] : 0.f;
    toT[g*KPAD + l] = f2bf(tv);
  }
  for (int l = 0; l < KPAD; ++l) {
    float fv = (g < NG && l < L2C) ? (float)(wg * Y[l]) : 0.f;
    frT[l*GPAD + g] = f2bf(fv);
  }
}

__global__ void convert_w_kernel(const float* __restrict__ w1, const float* __restrict__ w2,
                                 short* __restrict__ wb1, short* __restrict__ wb2) {
  const int i = blockIdx.x * 256 + threadIdx.x;
  if (i < 5*CH*CH) { wb1[i] = f2bf(w1[i]); wb2[i] = f2bf(w2[i]); }
}

// ================= fused: LN -> linear1 -> Gaunt(reg) -> linear2 + residual =================
__global__ __launch_bounds__(512, 4) void eqv3_fused4(
    const float* __restrict__ x,
    const float* __restrict__ norm_w, const float* __restrict__ norm_b,
    const short* __restrict__ wb1, const float* __restrict__ b1,
    const float* __restrict__ w_tp,
    const short* __restrict__ wb2, const float* __restrict__ b2,
    const short* __restrict__ toT, const short* __restrict__ frT,
    float* __restrict__ out)
{
  __shared__ __align__(16) short hsh[16][HROWS][8];   // 37632 B: LN-out / Gaunt-out staging
  __shared__ __align__(16) short hg[NB][4][CH][8];    // 32768 B: linear1 out (wave-private cols)
  __shared__ float red[8][3];

  const int tid  = threadIdx.x;
  const int w    = tid >> 6;
  const int lane = tid & 63;
  const int l16  = lane & 15;
  const int lq   = lane >> 4;
  const long n0  = (long)blockIdx.x * NB;

  constexpr int LDEG[L2C] = {0,1,1,1,2,2,2,2,2,3,3,3,3,3,3,3,4,4,4,4,4,4,4,4,4};
  constexpr int BROW[5]   = {0,16,32,64,96};   // padded degree-block starts (rows = sl*4+node)
  constexpr int NT[5]     = {1,1,2,2,3};       // 16-row M-tiles per degree

  const int nd = w >> 1;    // node this wave helps with (2 waves/node)
  const int hh = w & 1;     // half index within the node
  const int k  = w*16 + l16;  // this wave's output-channel column (linears) == Gaunt channel

  // zero hg slots s=28..31 (K-dim of to-grid MFMA must be clean); wave-private columns
  *(short4v*)&hg[lq][3][k][4] = (short4v){0,0,0,0};

  // ---- LayerNorm stats: 2 waves per node ----
  {
    const float2* x2 = (const float2*)(x + (n0 + nd) * (L2C*CH));
    float s0 = 0.f, s0q = 0.f, sq = 0.f;
    for (int it = 0; it < 13; ++it) {
      const int j = it*128 + hh*64 + lane;
      if (j < L2C*CH/2) {
        const float2 v = x2[j];
        const float t = v.x*v.x + v.y*v.y;
        if (j < 64) { s0 += v.x + v.y; s0q += t; }
        else        sq += t;
      }
    }
    #pragma unroll
    for (int o = 1; o < 64; o <<= 1) {
      s0  += __shfl_xor(s0,  o, 64);
      s0q += __shfl_xor(s0q, o, 64);
      sq  += __shfl_xor(sq,  o, 64);
    }
    if (lane == 0) { red[w][0] = s0; red[w][1] = s0q; red[w][2] = sq; }
  }
  __syncthreads();

  // ---- normalize + affine -> hsh (each wave writes its node's rows, split by s) ----
  {
    const float mean0 = (red[2*nd][0] + red[2*nd+1][0]) * (1.f/CH);
    const float var   = (red[2*nd][1] + red[2*nd+1][1] + red[2*nd][2] + red[2*nd+1][2]
                         - CH*mean0*mean0) * (1.f/(L2C*CH));
    const float rstd  = rsqrtf(var + 1e-5f);
    const float2* x2 = (const float2*)(x + (n0 + nd) * (L2C*CH));
    const int c0 = 2*lane;
    const int sBeg = hh ? 13 : 0;
    const int sEnd = hh ? 25 : 13;
    for (int s = sBeg; s < sEnd; ++s) {
      const int d   = LDEG[s];
      const int row = BROW[d] + (s - d*d)*NB + nd;
      const float2 v = x2[s*64 + lane];
      float a0 = v.x, a1 = v.y;
      if (s == 0) { a0 -= mean0; a1 -= mean0; }
      a0 *= rstd * norm_w[d*CH + c0];
      a1 *= rstd * norm_w[d*CH + c0 + 1];
      if (s == 0) { a0 += norm_b[c0]; a1 += norm_b[c0+1]; }
      *(unsigned*)&hsh[c0 >> 3][row][c0 & 7] = cvt_pk_bf16(a0, a1);
    }
  }
  __syncthreads();

  // ---- linear1 -> hg (wave-private k columns; no barrier after) ----
  {
    const float b1k = b1[k];
    #pragma unroll
    for (int d = 0; d < 5; ++d) {
      frag_u B[4];
      #pragma unroll
      for (int ks = 0; ks < 4; ++ks)
        B[ks].i = *(const i32x4*)(wb1 + ((d*CH + k)*CH + ks*32 + lq*8));
      #pragma unroll
      for (int mt = 0; mt < NT[d]; ++mt) {
        f32x4 acc = {0.f, 0.f, 0.f, 0.f};
        #pragma unroll
        for (int ks = 0; ks < 4; ++ks) {
          const bf16x8 a = *(const bf16x8*)&hsh[ks*4 + lq][BROW[d] + mt*16 + l16][0];
          acc = __builtin_amdgcn_mfma_f32_16x16x32_bf16(a, B[ks].h, acc, 0, 0, 0);
        }
        const int sl = mt*4 + lq;           // C row = sl*4 + node, node = acc index i
        const int s  = d*d + sl;
        if (sl <= 2*d) {
          #pragma unroll
          for (int i = 0; i < 4; ++i)
            hg[i][s >> 3][k][s & 7] = f2bf(acc[i] + ((s == 0) ? b1k : 0.f));
        } else if (d == 4) {                // unclaimed slots s=25..27 -> zero (K-dim hygiene)
          #pragma unroll
          for (int i = 0; i < 4; ++i) hg[i][s >> 3][k][s & 7] = 0;
        }
      }
    }
  }
  __syncthreads();   // all linear1 A-reads of hsh done before Gaunt overwrites it

  // ---- Gaunt per node, registers + bpermute (no LDS for grid values) ----
  {
    frag_u Ato[6];
    #pragma unroll
    for (int gt = 0; gt < 6; ++gt)
      Ato[gt].i = *(const i32x4*)(toT + (gt*16 + l16)*KPAD + lq*8);
    frag_u Afr[2][3];
    #pragma unroll
    for (int mt = 0; mt < 2; ++mt)
      #pragma unroll
      for (int ks = 0; ks < 3; ++ks)
        Afr[mt][ks].i = *(const i32x4*)(frT + (mt*16 + l16)*GPAD + ks*32 + lq*8);

    const bool hi32 = (lane >= 32);
    const int idxA = (l16 + 32*(lq & 1)) * 4;
    const int idxB = idxA + 64;

    float wtp[2][4]; int hrow[2][4];
    #pragma unroll
    for (int mt = 0; mt < 2; ++mt)
      #pragma unroll
      for (int i = 0; i < 4; ++i) {
        const int l = mt*16 + lq*4 + i;
        if (l < L2C) {
          const int d = LDEG[l];
          wtp[mt][i]  = w_tp[d*CH + k];
          hrow[mt][i] = BROW[d] + (l - d*d)*NB;
        } else { wtp[mt][i] = 0.f; hrow[mt][i] = -1; }
      }

    for (int node = 0; node < NB; ++node) {
      frag_u Bh;
      Bh.i = *(const i32x4*)&hg[node][lq][k][0];

      unsigned p[6][2];
      #pragma unroll
      for (int gt = 0; gt < 6; ++gt) {
        f32x4 acc = {0.f, 0.f, 0.f, 0.f};
        acc = __builtin_amdgcn_mfma_f32_16x16x32_bf16(Ato[gt].h, Bh.h, acc, 0, 0, 0);
        p[gt][0] = cvt_pk_bf16(acc[0]*acc[0], acc[1]*acc[1]);
        p[gt][1] = cvt_pk_bf16(acc[2]*acc[2], acc[3]*acc[3]);
      }

      f32x4 acc2[2] = {{0.f,0.f,0.f,0.f},{0.f,0.f,0.f,0.f}};
      #pragma unroll
      for (int ks = 0; ks < 3; ++ks) {
        frag_u Bg;
        {
          const int lo0 = __builtin_amdgcn_ds_bpermute(idxA, (int)p[2*ks][0]);
          const int hi0 = __builtin_amdgcn_ds_bpermute(idxA, (int)p[2*ks+1][0]);
          const int lo1 = __builtin_amdgcn_ds_bpermute(idxA, (int)p[2*ks][1]);
          const int hi1 = __builtin_amdgcn_ds_bpermute(idxA, (int)p[2*ks+1][1]);
          const int lo2 = __builtin_amdgcn_ds_bpermute(idxB, (int)p[2*ks][0]);
          const int hi2 = __builtin_amdgcn_ds_bpermute(idxB, (int)p[2*ks+1][0]);
          const int lo3 = __builtin_amdgcn_ds_bpermute(idxB, (int)p[2*ks][1]);
          const int hi3 = __builtin_amdgcn_ds_bpermute(idxB, (int)p[2*ks+1][1]);
          Bg.i[0] = hi32 ? hi0 : lo0;
          Bg.i[1] = hi32 ? hi1 : lo1;
          Bg.i[2] = hi32 ? hi2 : lo2;
          Bg.i[3] = hi32 ? hi3 : lo3;
        }
        #pragma unroll
        for (int mt = 0; mt < 2; ++mt)
          acc2[mt] = __builtin_amdgcn_mfma_f32_16x16x32_bf16(Afr[mt][ks].h, Bg.h, acc2[mt], 0, 0, 0);
      }
      #pragma unroll
      for (int mt = 0; mt < 2; ++mt)
        #pragma unroll
        for (int i = 0; i < 4; ++i)
          if (hrow[mt][i] >= 0)
            hsh[k >> 3][hrow[mt][i] + node][k & 7] = f2bf(acc2[mt][i] * wtp[mt][i]);
    }
  }
  __syncthreads();   // Gaunt output complete before linear2 reads

  // ---- linear2 + bias(l=0) + residual -> out ----
  {
    const float b2k = b2[k];
    #pragma unroll
    for (int d = 0; d < 5; ++d) {
      frag_u B[4];
      #pragma unroll
      for (int ks = 0; ks < 4; ++ks)
        B[ks].i = *(const i32x4*)(wb2 + ((d*CH + k)*CH + ks*32 + lq*8));
      #pragma unroll
      for (int mt = 0; mt < NT[d]; ++mt) {
        f32x4 acc = {0.f, 0.f, 0.f, 0.f};
        #pragma unroll
        for (int ks = 0; ks < 4; ++ks) {
          const bf16x8 a = *(const bf16x8*)&hsh[ks*4 + lq][BROW[d] + mt*16 + l16][0];
          acc = __builtin_amdgcn_mfma_f32_16x16x32_bf16(a, B[ks].h, acc, 0, 0, 0);
        }
        const int sl = mt*4 + lq;
        if (sl <= 2*d) {
          const int s = d*d + sl;
          #pragma unroll
          for (int i = 0; i < 4; ++i) {
            const long base = (n0 + i)*(long)(L2C*CH) + s*CH + k;
            out[base] = acc[i] + ((s == 0) ? b2k : 0.f) + x[base];
          }
        }
      }
    }
  }
}

// ---------------- launch ----------------
extern "C" void kernel_launch(void* const* d_in, const int* in_sizes, int n_in,
                              void* d_out, int out_size, void* d_ws, size_t ws_size,
                              hipStream_t stream) {
  const float* x      = (const float*)d_in[0];
  // d_in[1] = batch (unused)
  const float* norm_w = (const float*)d_in[2];
  const float* norm_b = (const float*)d_in[3];
  const float* w1     = (const float*)d_in[4];
  const float* b1     = (const float*)d_in[5];
  const float* w_tp   = (const float*)d_in[6];
  const float* w2     = (const float*)d_in[7];
  const float* b2     = (const float*)d_in[8];
  float* out = (float*)d_out;

  const int N = in_sizes[0] / (L2C*CH);   // 6000

  short* wsS = (short*)d_ws;              // ~670 KB
  short* toT = wsS;                       // [96][32]
  short* frT = toT + GPAD*KPAD;           // [32][96]
  short* wb1 = frT + KPAD*GPAD;           // [5][128][128]
  short* wb2 = wb1 + 5*CH*CH;

  build_tables_kernel<<<1, 128, 0, stream>>>(toT, frT);
  convert_w_kernel<<<(5*CH*CH + 255)/256, 256, 0, stream>>>(w1, w2, wb1, wb2);
  eqv3_fused4<<<N/NB, 512, 0, stream>>>(x, norm_w, norm_b, wb1, b1, w_tp, wb2, b2, toT, frT, out);
}

// Round 5
// 131.393 us; speedup vs baseline: 1.1161x; 1.0855x over previous
//
#include <hip/hip_runtime.h>
#include <math.h>

#define L2C 25
#define CH  128
#define NB  8
#define GLB 7
#define GLA 13
#define NG  91
#define GPAD 96
#define KPAD 32
#define HROWS 242

typedef short bf16x8 __attribute__((ext_vector_type(8)));
typedef int   i32x4  __attribute__((ext_vector_type(4)));
typedef float f32x4  __attribute__((ext_vector_type(4)));

union frag_u { i32x4 i; bf16x8 h; };

__device__ inline short f2bf(float f) {
  union { float f; unsigned u; } v; v.f = f;
  unsigned r = (v.u + 0x7FFFu + ((v.u >> 16) & 1u)) >> 16;
  return (short)r;
}
// plain (non-volatile) asm: pure, reorderable by the scheduler
__device__ inline unsigned cvt_pk_bf16(float lo, float hi) {
  unsigned r; asm("v_cvt_pk_bf16_f32 %0, %1, %2" : "=v"(r) : "v"(lo), "v"(hi)); return r;
}

// ---------------- SH tables (bf16), built on device ----------------
__global__ void build_tables_kernel(short* __restrict__ toT, short* __restrict__ frT) {
  const int g = threadIdx.x;
  if (g >= GPAD) return;
  const double PI = 3.14159265358979323846;
  double Y[L2C];
  double wg = 0.0;
  if (g < NG) {
    const int b = g / GLA;
    const int a = g % GLA;
    double xx = cos(PI * (b + 0.75) / (GLB + 0.5));
    double pp = 1.0;
    for (int it = 0; it < 64; ++it) {
      double p0 = 1.0, p1 = xx;
      for (int j = 2; j <= GLB; ++j) { double p2 = ((2.0*j-1.0)*xx*p1 - (j-1.0)*p0)/j; p0 = p1; p1 = p2; }
      pp = GLB * (xx*p1 - p0) / (xx*xx - 1.0);
      xx -= p1 / pp;
    }
    { double p0 = 1.0, p1 = xx;
      for (int j = 2; j <= GLB; ++j) { double p2 = ((2.0*j-1.0)*xx*p1 - (j-1.0)*p0)/j; p0 = p1; p1 = p2; }
      pp = GLB * (xx*p1 - p0) / (xx*xx - 1.0); }
    const double wb = 2.0 / ((1.0 - xx*xx) * pp * pp);
    const double ct = xx;
    const double sx = sqrt(fmax(0.0, 1.0 - ct*ct));
    double P[5][5];
    P[0][0] = 1.0;
    for (int m = 1; m <= 4; ++m) P[m][m] = -(2.0*m - 1.0) * sx * P[m-1][m-1];
    for (int m = 0; m <= 3; ++m) P[m+1][m] = (2.0*m + 1.0) * ct * P[m][m];
    for (int m = 0; m <= 4; ++m)
      for (int l = m + 2; l <= 4; ++l)
        P[l][m] = ((2.0*l-1.0)*ct*P[l-1][m] - (l+m-1.0)*P[l-2][m]) / (l - m);
    const double fact[9] = {1,1,2,6,24,120,720,5040,40320};
    const double phi = (2.0*PI/GLA) * a;
    for (int l = 0; l <= 4; ++l)
      for (int m = 0; m <= l; ++m) {
        double Nlm = sqrt((2.0*l+1.0)/(4.0*PI) * fact[l-m]/fact[l+m]);
        if (m == 0) Y[l*l + l] = Nlm * P[l][0];
        else {
          double base = sqrt(2.0) * Nlm * P[l][m];
          Y[l*l + l + m] = base * cos((double)m * phi);
          Y[l*l + l - m] = base * sin((double)m * phi);
        }
      }
    wg = wb * (2.0*PI/GLA);
  }
  for (int l = 0; l < KPAD; ++l) {
    float tv = (g < NG && l < L2C) ? (float)Y[l] : 0.f;
    toT[g*KPAD + l] = f2bf(tv);
  }
  for (int l = 0; l < KPAD; ++l) {
    float fv = (g < NG && l < L2C) ? (float)(wg * Y[l]) : 0.f;
    frT[l*GPAD + g] = f2bf(fv);
  }
}

__global__ void convert_w_kernel(const float* __restrict__ w1, const float* __restrict__ w2,
                                 short* __restrict__ wb1, short* __restrict__ wb2) {
  const int i = blockIdx.x * 256 + threadIdx.x;
  if (i < 5*CH*CH) { wb1[i] = f2bf(w1[i]); wb2[i] = f2bf(w2[i]); }
}

// ========== fused: LN(in-reg) -> lin1 -> Gaunt(reg+bpermute, unroll2) -> lin2 + residual ==========
__global__ __launch_bounds__(512, 2) void eqv3_fused8(
    const float* __restrict__ x,
    const float* __restrict__ norm_w, const float* __restrict__ norm_b,
    const short* __restrict__ wb1, const float* __restrict__ b1,
    const float* __restrict__ w_tp,
    const short* __restrict__ wb2, const float* __restrict__ b2,
    const short* __restrict__ toT, const short* __restrict__ frT,
    float* __restrict__ out)
{
  __shared__ __align__(16) short hsh[16][HROWS][8];   // 61,952 B
  __shared__ __align__(16) short hg[NB][4][CH][8];    // 65,536 B  (wave-private k columns)

  const int tid  = threadIdx.x;
  const int w    = tid >> 6;
  const int lane = tid & 63;
  const int l16  = lane & 15;
  const int lq   = lane >> 4;
  const long n0  = (long)blockIdx.x * NB;
  const int k    = w*16 + l16;    // this wave's channel column

  constexpr int LDEG[L2C] = {0,1,1,1,2,2,2,2,2,3,3,3,3,3,3,3,4,4,4,4,4,4,4,4,4};
  constexpr int BROW[5]   = {0,16,48,96,160};   // degree blocks, rows = (s-d*d)*8 + node
  constexpr int NT[5]     = {1,2,3,4,5};        // 16-row M-tiles per degree (sum 15)

  // ---- deep prefetch: lin1 weights + Gaunt tables (hidden under LN x-load) ----
  frag_u B1[5][4];
  #pragma unroll
  for (int d = 0; d < 5; ++d)
    #pragma unroll
    for (int ks = 0; ks < 4; ++ks)
      B1[d][ks].i = *(const i32x4*)(wb1 + ((d*CH + k)*CH + ks*32 + lq*8));
  frag_u Ato[6];
  #pragma unroll
  for (int gt = 0; gt < 6; ++gt)
    Ato[gt].i = *(const i32x4*)(toT + (gt*16 + l16)*KPAD + lq*8);
  frag_u Afr[2][3];
  #pragma unroll
  for (int mt = 0; mt < 2; ++mt)
    #pragma unroll
    for (int ks = 0; ks < 3; ++ks)
      Afr[mt][ks].i = *(const i32x4*)(frT + (mt*16 + l16)*GPAD + ks*32 + lq*8);

  // ---- zero hg s-chunk 3 (slots 24..31) for this wave's k columns; slot 24 rewritten by lin1 ----
  {
    const i32x4 z = {0,0,0,0};
    #pragma unroll
    for (int n = 0; n < NB; ++n) *(i32x4*)&hg[n][3][k][0] = z;
  }

  // ---- LayerNorm fully in registers: wave w owns node w ----
  {
    const float2* x2 = (const float2*)(x + (n0 + w)*(long)(L2C*CH));
    float2 xv[25];
    #pragma unroll
    for (int s = 0; s < 25; ++s) xv[s] = x2[s*64 + lane];
    const int c0 = 2*lane;
    float nwv[5][2];
    #pragma unroll
    for (int d = 0; d < 5; ++d) {
      const float2 t = ((const float2*)(norm_w + d*CH))[lane];
      nwv[d][0] = t.x; nwv[d][1] = t.y;
    }
    const float2 nbv = ((const float2*)norm_b)[lane];

    float s0  = xv[0].x + xv[0].y;
    float s0q = xv[0].x*xv[0].x + xv[0].y*xv[0].y;
    float sq  = 0.f;
    #pragma unroll
    for (int s = 1; s < 25; ++s) sq += xv[s].x*xv[s].x + xv[s].y*xv[s].y;
    #pragma unroll
    for (int o = 1; o < 64; o <<= 1) {
      s0  += __shfl_xor(s0,  o, 64);
      s0q += __shfl_xor(s0q, o, 64);
      sq  += __shfl_xor(sq,  o, 64);
    }
    const float mean0 = s0 * (1.f/CH);
    const float var   = (sq + s0q - CH*mean0*mean0) * (1.f/(L2C*CH));
    const float rstd  = rsqrtf(var + 1e-5f);
    #pragma unroll
    for (int s = 0; s < 25; ++s) {
      const int d   = LDEG[s];
      const int row = BROW[d] + (s - d*d)*NB + w;
      float a0 = xv[s].x, a1 = xv[s].y;
      if (s == 0) { a0 -= mean0; a1 -= mean0; }
      a0 *= rstd * nwv[d][0];
      a1 *= rstd * nwv[d][1];
      if (s == 0) { a0 += nbv.x; a1 += nbv.y; }
      *(unsigned*)&hsh[c0 >> 3][row][c0 & 7] = cvt_pk_bf16(a0, a1);
    }
  }
  __syncthreads();   // LN staged

  // ---- linear1 -> hg (wave-private k columns) ----
  {
    const float b1k = b1[k];
    #pragma unroll
    for (int d = 0; d < 5; ++d) {
      #pragma unroll
      for (int mt = 0; mt < NT[d]; ++mt) {
        f32x4 acc = {0.f, 0.f, 0.f, 0.f};
        #pragma unroll
        for (int ks = 0; ks < 4; ++ks) {
          const bf16x8 a = *(const bf16x8*)&hsh[ks*4 + lq][BROW[d] + mt*16 + l16][0];
          acc = __builtin_amdgcn_mfma_f32_16x16x32_bf16(a, B1[d][ks].h, acc, 0, 0, 0);
        }
        const int sl = 2*mt + (lq >> 1);      // C row rr = mt*16+lq*4+i: node=(lq&1)*4+i, sl=rr>>3
        if (sl <= 2*d) {
          const int s = d*d + sl;
          #pragma unroll
          for (int i = 0; i < 4; ++i)
            hg[(lq & 1)*4 + i][s >> 3][k][s & 7] = f2bf(acc[i] + ((s == 0) ? b1k : 0.f));
        }
      }
    }
  }
  __syncthreads();   // all lin1 hsh-reads complete before Gaunt overwrites hsh

  // ---- Gaunt: registers + bpermute; all Bh prefetched; node loop unroll x2 ----
  {
    frag_u Bh[NB];
    #pragma unroll
    for (int n = 0; n < NB; ++n)
      Bh[n].i = *(const i32x4*)&hg[n][lq][k][0];

    const bool hi32 = (lane >= 32);
    const int idxA = (l16 + 32*(lq & 1)) * 4;
    const int idxB = idxA + 64;

    float wtp[2][4]; int hrowb[2][4];
    #pragma unroll
    for (int mt = 0; mt < 2; ++mt)
      #pragma unroll
      for (int i = 0; i < 4; ++i) {
        const int l = mt*16 + lq*4 + i;
        if (l < L2C) {
          const int d = LDEG[l];
          wtp[mt][i]   = w_tp[d*CH + k];
          hrowb[mt][i] = BROW[d] + (l - d*d)*NB;
        } else { wtp[mt][i] = 0.f; hrowb[mt][i] = -1; }
      }

    #pragma unroll 2
    for (int n = 0; n < NB; ++n) {
      unsigned p[6][2];
      #pragma unroll
      for (int gt = 0; gt < 6; ++gt) {
        f32x4 acc = {0.f, 0.f, 0.f, 0.f};
        acc = __builtin_amdgcn_mfma_f32_16x16x32_bf16(Ato[gt].h, Bh[n].h, acc, 0, 0, 0);
        p[gt][0] = cvt_pk_bf16(acc[0]*acc[0], acc[1]*acc[1]);
        p[gt][1] = cvt_pk_bf16(acc[2]*acc[2], acc[3]*acc[3]);
      }
      f32x4 acc2[2] = {{0.f,0.f,0.f,0.f},{0.f,0.f,0.f,0.f}};
      #pragma unroll
      for (int ks = 0; ks < 3; ++ks) {
        frag_u Bg;
        {
          const int lo0 = __builtin_amdgcn_ds_bpermute(idxA, (int)p[2*ks][0]);
          const int hi0 = __builtin_amdgcn_ds_bpermute(idxA, (int)p[2*ks+1][0]);
          const int lo1 = __builtin_amdgcn_ds_bpermute(idxA, (int)p[2*ks][1]);
          const int hi1 = __builtin_amdgcn_ds_bpermute(idxA, (int)p[2*ks+1][1]);
          const int lo2 = __builtin_amdgcn_ds_bpermute(idxB, (int)p[2*ks][0]);
          const int hi2 = __builtin_amdgcn_ds_bpermute(idxB, (int)p[2*ks+1][0]);
          const int lo3 = __builtin_amdgcn_ds_bpermute(idxB, (int)p[2*ks][1]);
          const int hi3 = __builtin_amdgcn_ds_bpermute(idxB, (int)p[2*ks+1][1]);
          Bg.i[0] = hi32 ? hi0 : lo0;
          Bg.i[1] = hi32 ? hi1 : lo1;
          Bg.i[2] = hi32 ? hi2 : lo2;
          Bg.i[3] = hi32 ? hi3 : lo3;
        }
        acc2[0] = __builtin_amdgcn_mfma_f32_16x16x32_bf16(Afr[0][ks].h, Bg.h, acc2[0], 0, 0, 0);
        acc2[1] = __builtin_amdgcn_mfma_f32_16x16x32_bf16(Afr[1][ks].h, Bg.h, acc2[1], 0, 0, 0);
      }
      #pragma unroll
      for (int mt = 0; mt < 2; ++mt)
        #pragma unroll
        for (int i = 0; i < 4; ++i)
          if (hrowb[mt][i] >= 0)
            hsh[k >> 3][hrowb[mt][i] + n][k & 7] = f2bf(acc2[mt][i] * wtp[mt][i]);
    }
  }

  // prefetch lin2 weights before the barrier (issue during Gaunt tail)
  frag_u B2[5][4];
  #pragma unroll
  for (int d = 0; d < 5; ++d)
    #pragma unroll
    for (int ks = 0; ks < 4; ++ks)
      B2[d][ks].i = *(const i32x4*)(wb2 + ((d*CH + k)*CH + ks*32 + lq*8));

  __syncthreads();   // Gaunt output staged

  // ---- linear2 + bias(l=0) + residual -> out ----
  {
    const float b2k = b2[k];
    #pragma unroll
    for (int d = 0; d < 5; ++d) {
      #pragma unroll
      for (int mt = 0; mt < NT[d]; ++mt) {
        f32x4 acc = {0.f, 0.f, 0.f, 0.f};
        #pragma unroll
        for (int ks = 0; ks < 4; ++ks) {
          const bf16x8 a = *(const bf16x8*)&hsh[ks*4 + lq][BROW[d] + mt*16 + l16][0];
          acc = __builtin_amdgcn_mfma_f32_16x16x32_bf16(a, B2[d][ks].h, acc, 0, 0, 0);
        }
        const int sl = 2*mt + (lq >> 1);
        if (sl <= 2*d) {
          const int s = d*d + sl;
          #pragma unroll
          for (int i = 0; i < 4; ++i) {
            const int node = (lq & 1)*4 + i;
            const long base = (n0 + node)*(long)(L2C*CH) + s*CH + k;
            out[base] = acc[i] + ((s == 0) ? b2k : 0.f) + x[base];
          }
        }
      }
    }
  }
}

// ---------------- launch ----------------
extern "C" void kernel_launch(void* const* d_in, const int* in_sizes, int n_in,
                              void* d_out, int out_size, void* d_ws, size_t ws_size,
                              hipStream_t stream) {
  const float* x      = (const float*)d_in[0];
  // d_in[1] = batch (unused)
  const float* norm_w = (const float*)d_in[2];
  const float* norm_b = (const float*)d_in[3];
  const float* w1     = (const float*)d_in[4];
  const float* b1     = (const float*)d_in[5];
  const float* w_tp   = (const float*)d_in[6];
  const float* w2     = (const float*)d_in[7];
  const float* b2     = (const float*)d_in[8];
  float* out = (float*)d_out;

  const int N = in_sizes[0] / (L2C*CH);   // 6000

  short* wsS = (short*)d_ws;              // ~670 KB
  short* toT = wsS;                       // [96][32]
  short* frT = toT + GPAD*KPAD;           // [32][96]
  short* wb1 = frT + KPAD*GPAD;           // [5][128][128]
  short* wb2 = wb1 + 5*CH*CH;

  build_tables_kernel<<<1, 128, 0, stream>>>(toT, frT);
  convert_w_kernel<<<(5*CH*CH + 255)/256, 256, 0, stream>>>(w1, w2, wb1, wb2);
  eqv3_fused8<<<N/NB, 512, 0, stream>>>(x, norm_w, norm_b, wb1, b1, w_tp, wb2, b2, toT, frT, out);
}

// Round 6
// 122.803 us; speedup vs baseline: 1.1942x; 1.0699x over previous
//
#include <hip/hip_runtime.h>
#include <math.h>

#define L2C 25
#define CH  128
#define NB  8
#define GLB 7
#define GLA 13
#define NG  91
#define GPAD 96
#define KPAD 32
#define HROWS 242

typedef short bf16x8 __attribute__((ext_vector_type(8)));
typedef short short4v __attribute__((ext_vector_type(4)));
typedef int   i32x4  __attribute__((ext_vector_type(4)));
typedef float f32x4  __attribute__((ext_vector_type(4)));
typedef unsigned uint2v __attribute__((ext_vector_type(2)));

union frag_u { i32x4 i; bf16x8 h; };

__device__ inline short f2bf(float f) {
  union { float f; unsigned u; } v; v.f = f;
  unsigned r = (v.u + 0x7FFFu + ((v.u >> 16) & 1u)) >> 16;
  return (short)r;
}
__device__ inline float bf2f(short s) {
  union { unsigned u; float f; } v; v.u = ((unsigned)(unsigned short)s) << 16; return v.f;
}
// plain (non-volatile): pure, reorderable
__device__ inline unsigned cvt_pk_bf16(float lo, float hi) {
  unsigned r; asm("v_cvt_pk_bf16_f32 %0, %1, %2" : "=v"(r) : "v"(lo), "v"(hi)); return r;
}

// ---------------- SH tables (bf16), built on device ----------------
__global__ void build_tables_kernel(short* __restrict__ toT, short* __restrict__ frT) {
  const int g = threadIdx.x;
  if (g >= GPAD) return;
  const double PI = 3.14159265358979323846;
  double Y[L2C];
  double wg = 0.0;
  if (g < NG) {
    const int b = g / GLA;
    const int a = g % GLA;
    double xx = cos(PI * (b + 0.75) / (GLB + 0.5));
    double pp = 1.0;
    for (int it = 0; it < 64; ++it) {
      double p0 = 1.0, p1 = xx;
      for (int j = 2; j <= GLB; ++j) { double p2 = ((2.0*j-1.0)*xx*p1 - (j-1.0)*p0)/j; p0 = p1; p1 = p2; }
      pp = GLB * (xx*p1 - p0) / (xx*xx - 1.0);
      xx -= p1 / pp;
    }
    { double p0 = 1.0, p1 = xx;
      for (int j = 2; j <= GLB; ++j) { double p2 = ((2.0*j-1.0)*xx*p1 - (j-1.0)*p0)/j; p0 = p1; p1 = p2; }
      pp = GLB * (xx*p1 - p0) / (xx*xx - 1.0); }
    const double wb = 2.0 / ((1.0 - xx*xx) * pp * pp);
    const double ct = xx;
    const double sx = sqrt(fmax(0.0, 1.0 - ct*ct));
    double P[5][5];
    P[0][0] = 1.0;
    for (int m = 1; m <= 4; ++m) P[m][m] = -(2.0*m - 1.0) * sx * P[m-1][m-1];
    for (int m = 0; m <= 3; ++m) P[m+1][m] = (2.0*m + 1.0) * ct * P[m][m];
    for (int m = 0; m <= 4; ++m)
      for (int l = m + 2; l <= 4; ++l)
        P[l][m] = ((2.0*l-1.0)*ct*P[l-1][m] - (l+m-1.0)*P[l-2][m]) / (l - m);
    const double fact[9] = {1,1,2,6,24,120,720,5040,40320};
    const double phi = (2.0*PI/GLA) * a;
    for (int l = 0; l <= 4; ++l)
      for (int m = 0; m <= l; ++m) {
        double Nlm = sqrt((2.0*l+1.0)/(4.0*PI) * fact[l-m]/fact[l+m]);
        if (m == 0) Y[l*l + l] = Nlm * P[l][0];
        else {
          double base = sqrt(2.0) * Nlm * P[l][m];
          Y[l*l + l + m] = base * cos((double)m * phi);
          Y[l*l + l - m] = base * sin((double)m * phi);
        }
      }
    wg = wb * (2.0*PI/GLA);
  }
  for (int l = 0; l < KPAD; ++l) {
    float tv = (g < NG && l < L2C) ? (float)Y[l] : 0.f;
    toT[g*KPAD + l] = f2bf(tv);
  }
  for (int l = 0; l < KPAD; ++l) {
    float fv = (g < NG && l < L2C) ? (float)(wg * Y[l]) : 0.f;
    frT[l*GPAD + g] = f2bf(fv);
  }
}

__global__ void convert_w_kernel(const float* __restrict__ w1, const float* __restrict__ w2,
                                 short* __restrict__ wb1, short* __restrict__ wb2) {
  const int i = blockIdx.x * 256 + threadIdx.x;
  if (i < 5*CH*CH) { wb1[i] = f2bf(w1[i]); wb2[i] = f2bf(w2[i]); }
}

// ========== fused: LN(f4,in-reg) -> lin1 -> Gaunt(2-stream) -> lin2 -> staged f4 epilogue ==========
__global__ __launch_bounds__(512, 2) void eqv3_fused8(
    const float* __restrict__ x,
    const float* __restrict__ norm_w, const float* __restrict__ norm_b,
    const short* __restrict__ wb1, const float* __restrict__ b1,
    const float* __restrict__ w_tp,
    const short* __restrict__ wb2, const float* __restrict__ b2,
    const short* __restrict__ toT, const short* __restrict__ frT,
    float* __restrict__ out)
{
  __shared__ __align__(16) short hsh[16][HROWS][8];   // 61,952 B
  __shared__ __align__(16) short hg[NB][4][CH][8];    // 65,536 B (lin1 out; later: lin2 staging)

  const int tid  = threadIdx.x;
  const int w    = tid >> 6;
  const int lane = tid & 63;
  const int l16  = lane & 15;
  const int lq   = lane >> 4;
  const long n0  = (long)blockIdx.x * NB;
  const int k    = w*16 + l16;    // this wave's channel column

  constexpr int LDEG[L2C] = {0,1,1,1,2,2,2,2,2,3,3,3,3,3,3,3,4,4,4,4,4,4,4,4,4};
  constexpr int BROW[5]   = {0,16,48,96,160};   // = 8*d*(d+1); rows = (s-d*d)*8 + node
  constexpr int NT[5]     = {1,2,3,4,5};        // 16-row M-tiles per degree

  // ---- zero hg s-chunk 3 (slots 24..31) for this wave's k columns (slot 24 rewritten by lin1) ----
  {
    const i32x4 z = {0,0,0,0};
    #pragma unroll
    for (int n = 0; n < NB; ++n) *(i32x4*)&hg[n][3][k][0] = z;
  }

  // ---- LayerNorm: wave w owns node w; x read ONCE as float4, held in regs ----
  {
    const float4* x4 = (const float4*)(x + (n0 + w)*(long)(L2C*CH));
    float4 xv[13];
    float s0 = 0.f, s0q = 0.f, sq = 0.f;
    #pragma unroll
    for (int it = 0; it < 13; ++it) {
      const int j = it*64 + lane;
      if (j < 800) {
        xv[it] = x4[j];
        const float t = xv[it].x*xv[it].x + xv[it].y*xv[it].y + xv[it].z*xv[it].z + xv[it].w*xv[it].w;
        if (j < 32) { s0 += xv[it].x + xv[it].y + xv[it].z + xv[it].w; s0q += t; }
        else        sq += t;
      }
    }
    #pragma unroll
    for (int o = 1; o < 64; o <<= 1) {
      s0  += __shfl_xor(s0,  o, 64);
      s0q += __shfl_xor(s0q, o, 64);
      sq  += __shfl_xor(sq,  o, 64);
    }
    const float mean0 = s0 * (1.f/CH);
    const float var   = (sq + s0q - CH*mean0*mean0) * (1.f/(L2C*CH));
    const float rstd  = rsqrtf(var + 1e-5f);
    #pragma unroll
    for (int it = 0; it < 13; ++it) {
      const int j = it*64 + lane;
      if (j < 800) {
        const int s = j >> 5;                       // 2 values per wave-iteration
        const int d = (int)sqrtf((float)s + 0.5f);  // exact floor-sqrt for s<25
        const int row = 8*(s + d) + w;
        const int c32 = j & 31;
        const int c0  = c32 * 4;
        const float4 nw4 = ((const float4*)norm_w)[d*32 + c32];
        float a0 = xv[it].x, a1 = xv[it].y, a2 = xv[it].z, a3 = xv[it].w;
        if (s == 0) {
          const float4 nb4 = ((const float4*)norm_b)[c32];
          a0 = (a0 - mean0)*rstd*nw4.x + nb4.x;
          a1 = (a1 - mean0)*rstd*nw4.y + nb4.y;
          a2 = (a2 - mean0)*rstd*nw4.z + nb4.z;
          a3 = (a3 - mean0)*rstd*nw4.w + nb4.w;
        } else {
          a0 *= rstd*nw4.x; a1 *= rstd*nw4.y; a2 *= rstd*nw4.z; a3 *= rstd*nw4.w;
        }
        uint2v pk; pk[0] = cvt_pk_bf16(a0, a1); pk[1] = cvt_pk_bf16(a2, a3);
        *(uint2v*)&hsh[c0 >> 3][row][c0 & 7] = pk;
      }
    }
  }
  __syncthreads();   // (1) LN staged

  // ---- linear1 -> hg (wave-private k columns) ----
  {
    const float b1k = b1[k];
    #pragma unroll
    for (int d = 0; d < 5; ++d) {
      frag_u B[4];
      #pragma unroll
      for (int ks = 0; ks < 4; ++ks)
        B[ks].i = *(const i32x4*)(wb1 + ((d*CH + k)*CH + ks*32 + lq*8));
      #pragma unroll
      for (int mt = 0; mt < NT[d]; ++mt) {
        f32x4 acc = {0.f, 0.f, 0.f, 0.f};
        #pragma unroll
        for (int ks = 0; ks < 4; ++ks) {
          const bf16x8 a = *(const bf16x8*)&hsh[ks*4 + lq][BROW[d] + mt*16 + l16][0];
          acc = __builtin_amdgcn_mfma_f32_16x16x32_bf16(a, B[ks].h, acc, 0, 0, 0);
        }
        const int sl = 2*mt + (lq >> 1);      // rr = mt*16+lq*4+i: node=(lq&1)*4+i, sl=rr>>3
        if (sl <= 2*d) {
          const int s = d*d + sl;
          #pragma unroll
          for (int i = 0; i < 4; ++i)
            hg[(lq & 1)*4 + i][s >> 3][k][s & 7] = f2bf(acc[i] + ((s == 0) ? b1k : 0.f));
        }
      }
    }
  }
  __syncthreads();   // (2) lin1 hsh-reads complete; Gaunt may overwrite hsh

  // ---- Gaunt: registers + bpermute; 2 independent node streams ----
  {
    frag_u Ato[6];
    #pragma unroll
    for (int gt = 0; gt < 6; ++gt)
      Ato[gt].i = *(const i32x4*)(toT + (gt*16 + l16)*KPAD + lq*8);
    frag_u Afr[2][3];
    #pragma unroll
    for (int mt = 0; mt < 2; ++mt)
      #pragma unroll
      for (int ks = 0; ks < 3; ++ks)
        Afr[mt][ks].i = *(const i32x4*)(frT + (mt*16 + l16)*GPAD + ks*32 + lq*8);

    frag_u Bh[NB];
    #pragma unroll
    for (int n = 0; n < NB; ++n)
      Bh[n].i = *(const i32x4*)&hg[n][lq][k][0];

    const bool hi32 = (lane >= 32);
    const int idxA = (l16 + 32*(lq & 1)) * 4;
    const int idxB = idxA + 64;

    float wtp[2][4]; int hrowb[2][4];
    #pragma unroll
    for (int mt = 0; mt < 2; ++mt)
      #pragma unroll
      for (int i = 0; i < 4; ++i) {
        const int l = mt*16 + lq*4 + i;
        if (l < L2C) {
          const int d = LDEG[l];
          wtp[mt][i]   = w_tp[d*CH + k];
          hrowb[mt][i] = BROW[d] + (l - d*d)*NB;
        } else { wtp[mt][i] = 0.f; hrowb[mt][i] = -1; }
      }

    #pragma unroll
    for (int np = 0; np < 4; ++np) {
      const int nA = np, nB2 = np + 4;
      unsigned pA[6][2], pB[6][2];
      #pragma unroll
      for (int gt = 0; gt < 6; ++gt) {
        f32x4 aA = {0.f,0.f,0.f,0.f}, aB = {0.f,0.f,0.f,0.f};
        aA = __builtin_amdgcn_mfma_f32_16x16x32_bf16(Ato[gt].h, Bh[nA].h,  aA, 0, 0, 0);
        aB = __builtin_amdgcn_mfma_f32_16x16x32_bf16(Ato[gt].h, Bh[nB2].h, aB, 0, 0, 0);
        pA[gt][0] = cvt_pk_bf16(aA[0]*aA[0], aA[1]*aA[1]);
        pA[gt][1] = cvt_pk_bf16(aA[2]*aA[2], aA[3]*aA[3]);
        pB[gt][0] = cvt_pk_bf16(aB[0]*aB[0], aB[1]*aB[1]);
        pB[gt][1] = cvt_pk_bf16(aB[2]*aB[2], aB[3]*aB[3]);
      }
      f32x4 acc2A[2] = {{0.f,0.f,0.f,0.f},{0.f,0.f,0.f,0.f}};
      f32x4 acc2B[2] = {{0.f,0.f,0.f,0.f},{0.f,0.f,0.f,0.f}};
      #pragma unroll
      for (int ks = 0; ks < 3; ++ks) {
        frag_u BgA, BgB;
        {
          const int a0 = __builtin_amdgcn_ds_bpermute(idxA, (int)pA[2*ks][0]);
          const int a1 = __builtin_amdgcn_ds_bpermute(idxA, (int)pA[2*ks+1][0]);
          const int a2 = __builtin_amdgcn_ds_bpermute(idxA, (int)pA[2*ks][1]);
          const int a3 = __builtin_amdgcn_ds_bpermute(idxA, (int)pA[2*ks+1][1]);
          const int a4 = __builtin_amdgcn_ds_bpermute(idxB, (int)pA[2*ks][0]);
          const int a5 = __builtin_amdgcn_ds_bpermute(idxB, (int)pA[2*ks+1][0]);
          const int a6 = __builtin_amdgcn_ds_bpermute(idxB, (int)pA[2*ks][1]);
          const int a7 = __builtin_amdgcn_ds_bpermute(idxB, (int)pA[2*ks+1][1]);
          BgA.i[0] = hi32 ? a1 : a0;
          BgA.i[1] = hi32 ? a3 : a2;
          BgA.i[2] = hi32 ? a5 : a4;
          BgA.i[3] = hi32 ? a7 : a6;
          const int b0 = __builtin_amdgcn_ds_bpermute(idxA, (int)pB[2*ks][0]);
          const int b1v = __builtin_amdgcn_ds_bpermute(idxA, (int)pB[2*ks+1][0]);
          const int b2v = __builtin_amdgcn_ds_bpermute(idxA, (int)pB[2*ks][1]);
          const int b3 = __builtin_amdgcn_ds_bpermute(idxA, (int)pB[2*ks+1][1]);
          const int b4 = __builtin_amdgcn_ds_bpermute(idxB, (int)pB[2*ks][0]);
          const int b5 = __builtin_amdgcn_ds_bpermute(idxB, (int)pB[2*ks+1][0]);
          const int b6 = __builtin_amdgcn_ds_bpermute(idxB, (int)pB[2*ks][1]);
          const int b7 = __builtin_amdgcn_ds_bpermute(idxB, (int)pB[2*ks+1][1]);
          BgB.i[0] = hi32 ? b1v : b0;
          BgB.i[1] = hi32 ? b3 : b2v;
          BgB.i[2] = hi32 ? b5 : b4;
          BgB.i[3] = hi32 ? b7 : b6;
        }
        acc2A[0] = __builtin_amdgcn_mfma_f32_16x16x32_bf16(Afr[0][ks].h, BgA.h, acc2A[0], 0, 0, 0);
        acc2A[1] = __builtin_amdgcn_mfma_f32_16x16x32_bf16(Afr[1][ks].h, BgA.h, acc2A[1], 0, 0, 0);
        acc2B[0] = __builtin_amdgcn_mfma_f32_16x16x32_bf16(Afr[0][ks].h, BgB.h, acc2B[0], 0, 0, 0);
        acc2B[1] = __builtin_amdgcn_mfma_f32_16x16x32_bf16(Afr[1][ks].h, BgB.h, acc2B[1], 0, 0, 0);
      }
      #pragma unroll
      for (int mt = 0; mt < 2; ++mt)
        #pragma unroll
        for (int i = 0; i < 4; ++i)
          if (hrowb[mt][i] >= 0) {
            hsh[k >> 3][hrowb[mt][i] + nA][k & 7]  = f2bf(acc2A[mt][i] * wtp[mt][i]);
            hsh[k >> 3][hrowb[mt][i] + nB2][k & 7] = f2bf(acc2B[mt][i] * wtp[mt][i]);
          }
    }
  }
  __syncthreads();   // (3) Gaunt output staged; hg free for lin2 staging

  // ---- linear2 + bias(l=0) -> staged bf16 in hg area, layout [n][s][c] ----
  {
    short* stg = &hg[0][0][0][0];   // 25600 shorts used
    const float b2k = b2[k];
    #pragma unroll
    for (int d = 0; d < 5; ++d) {
      frag_u B[4];
      #pragma unroll
      for (int ks = 0; ks < 4; ++ks)
        B[ks].i = *(const i32x4*)(wb2 + ((d*CH + k)*CH + ks*32 + lq*8));
      #pragma unroll
      for (int mt = 0; mt < NT[d]; ++mt) {
        f32x4 acc = {0.f, 0.f, 0.f, 0.f};
        #pragma unroll
        for (int ks = 0; ks < 4; ++ks) {
          const bf16x8 a = *(const bf16x8*)&hsh[ks*4 + lq][BROW[d] + mt*16 + l16][0];
          acc = __builtin_amdgcn_mfma_f32_16x16x32_bf16(a, B[ks].h, acc, 0, 0, 0);
        }
        const int sl = 2*mt + (lq >> 1);
        if (sl <= 2*d) {
          const int s = d*d + sl;
          #pragma unroll
          for (int i = 0; i < 4; ++i) {
            const int node = (lq & 1)*4 + i;
            stg[(node*L2C + s)*CH + k] = f2bf(acc[i] + ((s == 0) ? b2k : 0.f));
          }
        }
      }
    }
  }
  __syncthreads();   // (4) staged complete

  // ---- epilogue: out = staged + x, pure float4 streaming (x is L2-resident) ----
  {
    const short* stg = &hg[0][0][0][0];
    const float4* xs = (const float4*)(x + n0*(long)(L2C*CH));
    float4* os = (float4*)(out + n0*(long)(L2C*CH));
    for (int j = tid; j < NB*L2C*CH/4; j += 512) {
      const float4 xv4 = xs[j];
      const short4v sv = *(const short4v*)&stg[j*4];
      float4 o;
      o.x = bf2f(sv[0]) + xv4.x;
      o.y = bf2f(sv[1]) + xv4.y;
      o.z = bf2f(sv[2]) + xv4.z;
      o.w = bf2f(sv[3]) + xv4.w;
      os[j] = o;
    }
  }
}

// ---------------- launch ----------------
extern "C" void kernel_launch(void* const* d_in, const int* in_sizes, int n_in,
                              void* d_out, int out_size, void* d_ws, size_t ws_size,
                              hipStream_t stream) {
  const float* x      = (const float*)d_in[0];
  // d_in[1] = batch (unused)
  const float* norm_w = (const float*)d_in[2];
  const float* norm_b = (const float*)d_in[3];
  const float* w1     = (const float*)d_in[4];
  const float* b1     = (const float*)d_in[5];
  const float* w_tp   = (const float*)d_in[6];
  const float* w2     = (const float*)d_in[7];
  const float* b2     = (const float*)d_in[8];
  float* out = (float*)d_out;

  const int N = in_sizes[0] / (L2C*CH);   // 6000

  short* wsS = (short*)d_ws;              // ~670 KB
  short* toT = wsS;                       // [96][32]
  short* frT = toT + GPAD*KPAD;           // [32][96]
  short* wb1 = frT + KPAD*GPAD;           // [5][128][128]
  short* wb2 = wb1 + 5*CH*CH;

  build_tables_kernel<<<1, 128, 0, stream>>>(toT, frT);
  convert_w_kernel<<<(5*CH*CH + 255)/256, 256, 0, stream>>>(w1, w2, wb1, wb2);
  eqv3_fused8<<<N/NB, 512, 0, stream>>>(x, norm_w, norm_b, wb1, b1, w_tp, wb2, b2, toT, frT, out);
}

// Round 8
// 117.708 us; speedup vs baseline: 1.2459x; 1.0433x over previous
//
#include <hip/hip_runtime.h>
#include <math.h>

#define L2C 25
#define CH  128
#define NB  8
#define GLB 7
#define GLA 13
#define NG  91
#define GPAD 96
#define KPAD 32
#define HROWS 242

typedef short bf16x8 __attribute__((ext_vector_type(8)));
typedef short short4v __attribute__((ext_vector_type(4)));
typedef int   i32x4  __attribute__((ext_vector_type(4)));
typedef float f32x4  __attribute__((ext_vector_type(4)));
typedef unsigned uint2v __attribute__((ext_vector_type(2)));

union frag_u { i32x4 i; bf16x8 h; };

__device__ inline short f2bf(float f) {
  union { float f; unsigned u; } v; v.f = f;
  unsigned r = (v.u + 0x7FFFu + ((v.u >> 16) & 1u)) >> 16;
  return (short)r;
}
__device__ inline float bf2f(short s) {
  union { unsigned u; float f; } v; v.u = ((unsigned)(unsigned short)s) << 16; return v.f;
}
// plain (non-volatile): pure, reorderable
__device__ inline unsigned cvt_pk_bf16(float lo, float hi) {
  unsigned r; asm("v_cvt_pk_bf16_f32 %0, %1, %2" : "=v"(r) : "v"(lo), "v"(hi)); return r;
}

// ---------------- SH tables (bf16), built on device ----------------
// toT[g][s]: semantic s columns (as in R6). frT[l][kg]: kg-permuted columns so the
// from-grid B-frag is a direct register reinterpretation of the to-grid C-frags:
// physical g=(2ks+a)*16+lq*4+b  ->  kg = ks*32 + lq*8 + (a*4+b).
__global__ void build_tables_kernel(short* __restrict__ toT, short* __restrict__ frT) {
  const int g = threadIdx.x;
  if (g >= GPAD) return;
  const double PI = 3.14159265358979323846;
  double Y[L2C];
  double wg = 0.0;
  if (g < NG) {
    const int b = g / GLA;
    const int a = g % GLA;
    double xx = cos(PI * (b + 0.75) / (GLB + 0.5));
    double pp = 1.0;
    for (int it = 0; it < 64; ++it) {
      double p0 = 1.0, p1 = xx;
      for (int j = 2; j <= GLB; ++j) { double p2 = ((2.0*j-1.0)*xx*p1 - (j-1.0)*p0)/j; p0 = p1; p1 = p2; }
      pp = GLB * (xx*p1 - p0) / (xx*xx - 1.0);
      xx -= p1 / pp;
    }
    { double p0 = 1.0, p1 = xx;
      for (int j = 2; j <= GLB; ++j) { double p2 = ((2.0*j-1.0)*xx*p1 - (j-1.0)*p0)/j; p0 = p1; p1 = p2; }
      pp = GLB * (xx*p1 - p0) / (xx*xx - 1.0); }
    const double wb = 2.0 / ((1.0 - xx*xx) * pp * pp);
    const double ct = xx;
    const double sx = sqrt(fmax(0.0, 1.0 - ct*ct));
    double P[5][5];
    P[0][0] = 1.0;
    for (int m = 1; m <= 4; ++m) P[m][m] = -(2.0*m - 1.0) * sx * P[m-1][m-1];
    for (int m = 0; m <= 3; ++m) P[m+1][m] = (2.0*m + 1.0) * ct * P[m][m];
    for (int m = 0; m <= 4; ++m)
      for (int l = m + 2; l <= 4; ++l)
        P[l][m] = ((2.0*l-1.0)*ct*P[l-1][m] - (l+m-1.0)*P[l-2][m]) / (l - m);
    const double fact[9] = {1,1,2,6,24,120,720,5040,40320};
    const double phi = (2.0*PI/GLA) * a;
    for (int l = 0; l <= 4; ++l)
      for (int m = 0; m <= l; ++m) {
        double Nlm = sqrt((2.0*l+1.0)/(4.0*PI) * fact[l-m]/fact[l+m]);
        if (m == 0) Y[l*l + l] = Nlm * P[l][0];
        else {
          double base = sqrt(2.0) * Nlm * P[l][m];
          Y[l*l + l + m] = base * cos((double)m * phi);
          Y[l*l + l - m] = base * sin((double)m * phi);
        }
      }
    wg = wb * (2.0*PI/GLA);
  }
  for (int l = 0; l < KPAD; ++l) {
    float tv = (g < NG && l < L2C) ? (float)Y[l] : 0.f;
    toT[g*KPAD + l] = f2bf(tv);
  }
  {
    const int hi = g >> 4, r = g & 15;
    const int ksv = hi >> 1, pa = hi & 1;
    const int lqv = r >> 2,  pb = r & 3;
    const int u  = pa*4 + pb;
    const int kg = ksv*32 + lqv*8 + u;
    for (int l = 0; l < KPAD; ++l)
      frT[l*GPAD + kg] = (g < NG && l < L2C) ? f2bf((float)(wg * Y[l])) : (short)0;
  }
}

__global__ void convert_w_kernel(const float* __restrict__ w1, const float* __restrict__ w2,
                                 short* __restrict__ wb1, short* __restrict__ wb2) {
  const int i = blockIdx.x * 256 + threadIdx.x;
  if (i < 5*CH*CH) { wb1[i] = f2bf(w1[i]); wb2[i] = f2bf(w2[i]); }
}

// ========== fused: LN(f4,in-reg) -> lin1 -> Gaunt(2-stream, register handoff) -> lin2 -> staged f4 epilogue ==========
__global__ __launch_bounds__(512, 2) void eqv3_fused8(
    const float* __restrict__ x,
    const float* __restrict__ norm_w, const float* __restrict__ norm_b,
    const short* __restrict__ wb1, const float* __restrict__ b1,
    const float* __restrict__ w_tp,
    const short* __restrict__ wb2, const float* __restrict__ b2,
    const short* __restrict__ toT, const short* __restrict__ frT,
    float* __restrict__ out)
{
  __shared__ __align__(16) short hsh[16][HROWS][8];   // 61,952 B
  __shared__ __align__(16) short hg[NB][4][CH][8];    // 65,536 B (lin1 out; later: lin2 staging)

  const int tid  = threadIdx.x;
  const int w    = tid >> 6;
  const int lane = tid & 63;
  const int l16  = lane & 15;
  const int lq   = lane >> 4;
  const long n0  = (long)blockIdx.x * NB;
  const int k    = w*16 + l16;    // this wave's channel column

  constexpr int LDEG[L2C] = {0,1,1,1,2,2,2,2,2,3,3,3,3,3,3,3,4,4,4,4,4,4,4,4,4};
  constexpr int BROW[5]   = {0,16,48,96,160};   // = 8*d*(d+1); rows = (s-d*d)*8 + node
  constexpr int NT[5]     = {1,2,3,4,5};        // 16-row M-tiles per degree

  // ---- zero hg s-chunk 3 (slots 24..31) for this wave's k columns (slot 24 rewritten by lin1) ----
  {
    const i32x4 z = {0,0,0,0};
    #pragma unroll
    for (int n = 0; n < NB; ++n) *(i32x4*)&hg[n][3][k][0] = z;
  }

  // ---- LayerNorm: wave w owns node w; x read ONCE as float4, held in regs ----
  {
    const float4* x4 = (const float4*)(x + (n0 + w)*(long)(L2C*CH));
    float4 xv[13];
    float s0 = 0.f, s0q = 0.f, sq = 0.f;
    #pragma unroll
    for (int it = 0; it < 13; ++it) {
      const int j = it*64 + lane;
      if (j < 800) {
        xv[it] = x4[j];
        const float t = xv[it].x*xv[it].x + xv[it].y*xv[it].y + xv[it].z*xv[it].z + xv[it].w*xv[it].w;
        if (j < 32) { s0 += xv[it].x + xv[it].y + xv[it].z + xv[it].w; s0q += t; }
        else        sq += t;
      }
    }
    #pragma unroll
    for (int o = 1; o < 64; o <<= 1) {
      s0  += __shfl_xor(s0,  o, 64);
      s0q += __shfl_xor(s0q, o, 64);
      sq  += __shfl_xor(sq,  o, 64);
    }
    const float mean0 = s0 * (1.f/CH);
    const float var   = (sq + s0q - CH*mean0*mean0) * (1.f/(L2C*CH));
    const float rstd  = rsqrtf(var + 1e-5f);
    #pragma unroll
    for (int it = 0; it < 13; ++it) {
      const int j = it*64 + lane;
      if (j < 800) {
        const int s = j >> 5;                       // 2 values per wave-iteration
        const int d = (int)sqrtf((float)s + 0.5f);  // exact floor-sqrt for s<25
        const int row = 8*(s + d) + w;
        const int c32 = j & 31;
        const int c0  = c32 * 4;
        const float4 nw4 = ((const float4*)norm_w)[d*32 + c32];
        float a0 = xv[it].x, a1 = xv[it].y, a2 = xv[it].z, a3 = xv[it].w;
        if (s == 0) {
          const float4 nb4 = ((const float4*)norm_b)[c32];
          a0 = (a0 - mean0)*rstd*nw4.x + nb4.x;
          a1 = (a1 - mean0)*rstd*nw4.y + nb4.y;
          a2 = (a2 - mean0)*rstd*nw4.z + nb4.z;
          a3 = (a3 - mean0)*rstd*nw4.w + nb4.w;
        } else {
          a0 *= rstd*nw4.x; a1 *= rstd*nw4.y; a2 *= rstd*nw4.z; a3 *= rstd*nw4.w;
        }
        uint2v pk; pk[0] = cvt_pk_bf16(a0, a1); pk[1] = cvt_pk_bf16(a2, a3);
        *(uint2v*)&hsh[c0 >> 3][row][c0 & 7] = pk;
      }
    }
  }
  __syncthreads();   // (1) LN staged

  // ---- linear1 -> hg (wave-private k columns) ----
  {
    const float b1k = b1[k];
    #pragma unroll
    for (int d = 0; d < 5; ++d) {
      frag_u B[4];
      #pragma unroll
      for (int ks = 0; ks < 4; ++ks)
        B[ks].i = *(const i32x4*)(wb1 + ((d*CH + k)*CH + ks*32 + lq*8));
      #pragma unroll
      for (int mt = 0; mt < NT[d]; ++mt) {
        f32x4 acc = {0.f, 0.f, 0.f, 0.f};
        #pragma unroll
        for (int ks = 0; ks < 4; ++ks) {
          const bf16x8 a = *(const bf16x8*)&hsh[ks*4 + lq][BROW[d] + mt*16 + l16][0];
          acc = __builtin_amdgcn_mfma_f32_16x16x32_bf16(a, B[ks].h, acc, 0, 0, 0);
        }
        const int sl = 2*mt + (lq >> 1);      // rr = mt*16+lq*4+i: node=(lq&1)*4+i, sl=rr>>3
        if (sl <= 2*d) {
          const int s = d*d + sl;
          #pragma unroll
          for (int i = 0; i < 4; ++i)
            hg[(lq & 1)*4 + i][s >> 3][k][s & 7] = f2bf(acc[i] + ((s == 0) ? b1k : 0.f));
        }
      }
    }
  }
  __syncthreads();   // (2) lin1 hsh-reads complete; Gaunt may overwrite hsh

  // ---- Gaunt: 2 independent node streams; from-grid B = register reinterpretation ----
  {
    frag_u Ato[6];
    #pragma unroll
    for (int gt = 0; gt < 6; ++gt)
      Ato[gt].i = *(const i32x4*)(toT + (gt*16 + l16)*KPAD + lq*8);
    frag_u Afr[2][3];
    #pragma unroll
    for (int mt = 0; mt < 2; ++mt)
      #pragma unroll
      for (int ks = 0; ks < 3; ++ks)
        Afr[mt][ks].i = *(const i32x4*)(frT + (mt*16 + l16)*GPAD + ks*32 + lq*8);

    frag_u Bh[NB];
    #pragma unroll
    for (int n = 0; n < NB; ++n)
      Bh[n].i = *(const i32x4*)&hg[n][lq][k][0];

    float wtp[2][4]; int hrowb[2][4];
    #pragma unroll
    for (int mt = 0; mt < 2; ++mt)
      #pragma unroll
      for (int i = 0; i < 4; ++i) {
        const int l = mt*16 + lq*4 + i;
        if (l < L2C) {
          const int d = LDEG[l];
          wtp[mt][i]   = w_tp[d*CH + k];
          hrowb[mt][i] = BROW[d] + (l - d*d)*NB;
        } else { wtp[mt][i] = 0.f; hrowb[mt][i] = -1; }
      }

    #pragma unroll
    for (int np = 0; np < 4; ++np) {
      const int nA = np, nB2 = np + 4;
      unsigned pA[6][2], pB[6][2];
      #pragma unroll
      for (int gt = 0; gt < 6; ++gt) {
        f32x4 aA = {0.f,0.f,0.f,0.f}, aB = {0.f,0.f,0.f,0.f};
        aA = __builtin_amdgcn_mfma_f32_16x16x32_bf16(Ato[gt].h, Bh[nA].h,  aA, 0, 0, 0);
        aB = __builtin_amdgcn_mfma_f32_16x16x32_bf16(Ato[gt].h, Bh[nB2].h, aB, 0, 0, 0);
        pA[gt][0] = cvt_pk_bf16(aA[0]*aA[0], aA[1]*aA[1]);
        pA[gt][1] = cvt_pk_bf16(aA[2]*aA[2], aA[3]*aA[3]);
        pB[gt][0] = cvt_pk_bf16(aB[0]*aB[0], aB[1]*aB[1]);
        pB[gt][1] = cvt_pk_bf16(aB[2]*aB[2], aB[3]*aB[3]);
      }
      f32x4 acc2A[2] = {{0.f,0.f,0.f,0.f},{0.f,0.f,0.f,0.f}};
      f32x4 acc2B[2] = {{0.f,0.f,0.f,0.f},{0.f,0.f,0.f,0.f}};
      #pragma unroll
      for (int ks = 0; ks < 3; ++ks) {
        frag_u BgA, BgB;
        BgA.i[0] = (int)pA[2*ks][0];   BgA.i[1] = (int)pA[2*ks][1];
        BgA.i[2] = (int)pA[2*ks+1][0]; BgA.i[3] = (int)pA[2*ks+1][1];
        BgB.i[0] = (int)pB[2*ks][0];   BgB.i[1] = (int)pB[2*ks][1];
        BgB.i[2] = (int)pB[2*ks+1][0]; BgB.i[3] = (int)pB[2*ks+1][1];
        acc2A[0] = __builtin_amdgcn_mfma_f32_16x16x32_bf16(Afr[0][ks].h, BgA.h, acc2A[0], 0, 0, 0);
        acc2A[1] = __builtin_amdgcn_mfma_f32_16x16x32_bf16(Afr[1][ks].h, BgA.h, acc2A[1], 0, 0, 0);
        acc2B[0] = __builtin_amdgcn_mfma_f32_16x16x32_bf16(Afr[0][ks].h, BgB.h, acc2B[0], 0, 0, 0);
        acc2B[1] = __builtin_amdgcn_mfma_f32_16x16x32_bf16(Afr[1][ks].h, BgB.h, acc2B[1], 0, 0, 0);
      }
      #pragma unroll
      for (int mt = 0; mt < 2; ++mt)
        #pragma unroll
        for (int i = 0; i < 4; ++i)
          if (hrowb[mt][i] >= 0) {
            hsh[k >> 3][hrowb[mt][i] + nA][k & 7]  = f2bf(acc2A[mt][i] * wtp[mt][i]);
            hsh[k >> 3][hrowb[mt][i] + nB2][k & 7] = f2bf(acc2B[mt][i] * wtp[mt][i]);
          }
    }
  }
  __syncthreads();   // (3) Gaunt output staged; hg free for lin2 staging

  // ---- linear2 + bias(l=0) -> staged bf16 in hg area, layout [n][s][c] ----
  {
    short* stg = &hg[0][0][0][0];   // 25600 shorts used
    const float b2k = b2[k];
    #pragma unroll
    for (int d = 0; d < 5; ++d) {
      frag_u B[4];
      #pragma unroll
      for (int ks = 0; ks < 4; ++ks)
        B[ks].i = *(const i32x4*)(wb2 + ((d*CH + k)*CH + ks*32 + lq*8));
      #pragma unroll
      for (int mt = 0; mt < NT[d]; ++mt) {
        f32x4 acc = {0.f, 0.f, 0.f, 0.f};
        #pragma unroll
        for (int ks = 0; ks < 4; ++ks) {
          const bf16x8 a = *(const bf16x8*)&hsh[ks*4 + lq][BROW[d] + mt*16 + l16][0];
          acc = __builtin_amdgcn_mfma_f32_16x16x32_bf16(a, B[ks].h, acc, 0, 0, 0);
        }
        const int sl = 2*mt + (lq >> 1);
        if (sl <= 2*d) {
          const int s = d*d + sl;
          #pragma unroll
          for (int i = 0; i < 4; ++i) {
            const int node = (lq & 1)*4 + i;
            stg[(node*L2C + s)*CH + k] = f2bf(acc[i] + ((s == 0) ? b2k : 0.f));
          }
        }
      }
    }
  }
  __syncthreads();   // (4) staged complete

  // ---- epilogue: out = staged + x, pure float4 streaming (x is L2-resident) ----
  {
    const short* stg = &hg[0][0][0][0];
    const float4* xs = (const float4*)(x + n0*(long)(L2C*CH));
    float4* os = (float4*)(out + n0*(long)(L2C*CH));
    for (int j = tid; j < NB*L2C*CH/4; j += 512) {
      const float4 xv4 = xs[j];
      const short4v sv = *(const short4v*)&stg[j*4];
      float4 o;
      o.x = bf2f(sv[0]) + xv4.x;
      o.y = bf2f(sv[1]) + xv4.y;
      o.z = bf2f(sv[2]) + xv4.z;
      o.w = bf2f(sv[3]) + xv4.w;
      os[j] = o;
    }
  }
}

// ---------------- launch ----------------
extern "C" void kernel_launch(void* const* d_in, const int* in_sizes, int n_in,
                              void* d_out, int out_size, void* d_ws, size_t ws_size,
                              hipStream_t stream) {
  const float* x      = (const float*)d_in[0];
  // d_in[1] = batch (unused)
  const float* norm_w = (const float*)d_in[2];
  const float* norm_b = (const float*)d_in[3];
  const float* w1     = (const float*)d_in[4];
  const float* b1     = (const float*)d_in[5];
  const float* w_tp   = (const float*)d_in[6];
  const float* w2     = (const float*)d_in[7];
  const float* b2     = (const float*)d_in[8];
  float* out = (float*)d_out;

  const int N = in_sizes[0] / (L2C*CH);   // 6000

  short* wsS = (short*)d_ws;              // ~670 KB
  short* toT = wsS;                       // [96][32]
  short* frT = toT + GPAD*KPAD;           // [32][96]
  short* wb1 = frT + KPAD*GPAD;           // [5][128][128]
  short* wb2 = wb1 + 5*CH*CH;

  build_tables_kernel<<<1, 128, 0, stream>>>(toT, frT);
  convert_w_kernel<<<(5*CH*CH + 255)/256, 256, 0, stream>>>(w1, w2, wb1, wb2);
  eqv3_fused8<<<N/NB, 512, 0, stream>>>(x, norm_w, norm_b, wb1, b1, w_tp, wb2, b2, toT, frT, out);
}